// Round 1
// baseline (1943.280 us; speedup 1.0000x reference)
//
#include <hip/hip_runtime.h>
#include <stdint.h>

#define N_EXPERTS 8
#define D_MODEL 1024
#define D_FF 4096
#define N_TOKENS 2048
#define ASSN 4096          // N_TOKENS * TOP_K
#define ROWS 4224          // ASSN + 128 slack rows for tile overrun
#define BK 32
#define SK 40              // padded LDS row stride (elems) for B tiles

using bfrag = __attribute__((ext_vector_type(8))) short;   // 8 x bf16
using f32x4 = __attribute__((ext_vector_type(4))) float;
typedef unsigned short u16;

__device__ __forceinline__ u16 f2bf(float f) {
  uint32_t u = __builtin_bit_cast(uint32_t, f);
  u += 0x7fffu + ((u >> 16) & 1u);   // round-to-nearest-even
  return (u16)(u >> 16);
}

__device__ __forceinline__ void gll16(const void* g, void* l) {
  __builtin_amdgcn_global_load_lds(
      (const __attribute__((address_space(1))) void*)g,
      (__attribute__((address_space(3))) void*)l, 16, 0, 0);
}

// ---------------- setup: bucket assignments by expert ----------------
__global__ void k_setup(const int* __restrict__ eidx, const float* __restrict__ ew,
                        int* __restrict__ rowmap, int* __restrict__ tokrow,
                        float* __restrict__ wrow, int* __restrict__ counts,
                        int* __restrict__ offs) {
  __shared__ int sc[N_EXPERTS], so[N_EXPERTS];
  int t = threadIdx.x;
  if (t < N_EXPERTS) sc[t] = 0;
  __syncthreads();
  for (int a = t; a < ASSN; a += 256) atomicAdd(&sc[eidx[a]], 1);
  __syncthreads();
  if (t == 0) {
    int run = 0;
    for (int e = 0; e < N_EXPERTS; e++) {
      counts[e] = sc[e]; offs[e] = run; so[e] = run; run += sc[e];
    }
  }
  __syncthreads();
  for (int a = t; a < ASSN; a += 256) {
    int e = eidx[a];
    int p = atomicAdd(&so[e], 1);
    rowmap[p] = a;
    tokrow[p] = a >> 1;     // TOP_K = 2
    wrow[p] = ew[a];
  }
}

// ---------------- gather x rows -> bf16 packed by expert ----------------
__global__ void k_gather(const float* __restrict__ x, const int* __restrict__ rowmap,
                         u16* __restrict__ Xg) {
  int r = blockIdx.x, t = threadIdx.x;
  uint2 o;
  if (r < ASSN) {
    int tok = rowmap[r] >> 1;
    float4 v = *(const float4*)(x + (size_t)tok * D_MODEL + t * 4);
    o.x = (uint32_t)f2bf(v.x) | ((uint32_t)f2bf(v.y) << 16);
    o.y = (uint32_t)f2bf(v.z) | ((uint32_t)f2bf(v.w) << 16);
  } else {
    o.x = 0u; o.y = 0u;    // zero slack rows
  }
  *(uint2*)(Xg + (size_t)r * D_MODEL + t * 4) = o;
}

// ---------------- GEMM1: H = silu(Xg@W1) * (Xg@W2), bf16 out ----------------
__launch_bounds__(256, 2)
__global__ void k_gemm1(const u16* __restrict__ Xg,
                        const float* __restrict__ w1, const float* __restrict__ w2,
                        const int* __restrict__ counts, const int* __restrict__ offs,
                        u16* __restrict__ H) {
  const int e = blockIdx.z, mt = blockIdx.x, nt = blockIdx.y;
  const int cnt = counts[e];
  if (mt * 128 >= cnt) return;
  const int row0 = offs[e] + mt * 128;
  const int mrem = cnt - mt * 128;
  const int n0 = nt * 128;
  const float* __restrict__ W1 = w1 + (size_t)e * D_MODEL * D_FF;
  const float* __restrict__ W2 = w2 + (size_t)e * D_MODEL * D_FF;

  __shared__ u16 As[128 * BK];     // [m][k], k contiguous (global_load_lds layout)
  __shared__ u16 Bs1[128 * SK];    // [n][k], k contiguous, padded stride
  __shared__ u16 Bs2[128 * SK];

  const int tid = threadIdx.x;
  const int lane = tid & 63, wave = tid >> 6;
  const int wm = (wave >> 1) << 6, wn = (wave & 1) << 6;
  const int l16 = lane & 15, quad = lane >> 4;

  // A staging: 2 calls x (256 lanes x 16B) covers 128x32 bf16
  const int aoff0 = (tid >> 2) * D_MODEL + (tid & 3) * 8;
  const int aoff1 = aoff0 + 64 * D_MODEL;
  u16* const ldsA0 = As + wave * 512;
  u16* const ldsA1 = As + wave * 512 + 2048;
  const u16* gA = Xg + (size_t)row0 * D_MODEL;

  // B staging: thread covers cols n2,n2+1 x 8 k's (fp32 -> bf16, transpose)
  const int n2 = (tid & 63) * 2;
  const int kh = (tid >> 6) * 8;
  const float* gB1 = W1 + (size_t)kh * D_FF + n0 + n2;
  const float* gB2 = W2 + (size_t)kh * D_FF + n0 + n2;
  u16* const wB1 = Bs1 + n2 * SK + kh;
  u16* const wB2 = Bs2 + n2 * SK + kh;

  f32x4 acc1[4][4] = {};
  f32x4 acc2[4][4] = {};

  for (int k0 = 0; k0 < D_MODEL; k0 += BK) {
    gll16(gA + aoff0, ldsA0);
    gll16(gA + aoff1, ldsA1);
    {
      float2 v[8];
      #pragma unroll
      for (int kk = 0; kk < 8; kk++) v[kk] = *(const float2*)(gB1 + (size_t)kk * D_FF);
      bfrag p0, p1;
      #pragma unroll
      for (int kk = 0; kk < 8; kk++) { p0[kk] = (short)f2bf(v[kk].x); p1[kk] = (short)f2bf(v[kk].y); }
      *(bfrag*)wB1 = p0;
      *(bfrag*)(wB1 + SK) = p1;
    }
    {
      float2 v[8];
      #pragma unroll
      for (int kk = 0; kk < 8; kk++) v[kk] = *(const float2*)(gB2 + (size_t)kk * D_FF);
      bfrag p0, p1;
      #pragma unroll
      for (int kk = 0; kk < 8; kk++) { p0[kk] = (short)f2bf(v[kk].x); p1[kk] = (short)f2bf(v[kk].y); }
      *(bfrag*)wB2 = p0;
      *(bfrag*)(wB2 + SK) = p1;
    }
    __syncthreads();
    bfrag b1[4], b2[4];
    #pragma unroll
    for (int j = 0; j < 4; j++) {
      b1[j] = *(const bfrag*)(Bs1 + (wn + j * 16 + l16) * SK + quad * 8);
      b2[j] = *(const bfrag*)(Bs2 + (wn + j * 16 + l16) * SK + quad * 8);
    }
    #pragma unroll
    for (int i = 0; i < 4; i++) {
      bfrag a = *(const bfrag*)(As + (wm + i * 16 + l16) * BK + quad * 8);
      #pragma unroll
      for (int j = 0; j < 4; j++) {
        acc1[i][j] = __builtin_amdgcn_mfma_f32_16x16x32_bf16(a, b1[j], acc1[i][j], 0, 0, 0);
        acc2[i][j] = __builtin_amdgcn_mfma_f32_16x16x32_bf16(a, b2[j], acc2[i][j], 0, 0, 0);
      }
    }
    __syncthreads();
    gA += BK;
    gB1 += (size_t)BK * D_FF;
    gB2 += (size_t)BK * D_FF;
  }

  // epilogue: h = silu(g)*v, store bf16. C/D layout: col=lane&15, row=quad*4+reg
  #pragma unroll
  for (int i = 0; i < 4; i++) {
    #pragma unroll
    for (int p = 0; p < 4; p++) {
      const int mloc = wm + i * 16 + quad * 4 + p;
      if (mloc < mrem) {
        u16* dst = H + (size_t)(row0 + mloc) * D_FF + n0 + wn + l16;
        #pragma unroll
        for (int j = 0; j < 4; j++) {
          float g = acc1[i][j][p];
          float vv = acc2[i][j][p];
          float h = g / (1.0f + __expf(-g)) * vv;
          dst[j * 16] = f2bf(h);
        }
      }
    }
  }
}

// ---------------- GEMM2: out[tok] += w * (H @ W3) ----------------
__launch_bounds__(256, 2)
__global__ void k_gemm2(const u16* __restrict__ H,
                        const float* __restrict__ w3,
                        const int* __restrict__ counts, const int* __restrict__ offs,
                        const int* __restrict__ tokrow, const float* __restrict__ wrow,
                        float* __restrict__ out) {
  const int e = blockIdx.z, mt = blockIdx.x, nt = blockIdx.y;
  const int cnt = counts[e];
  if (mt * 128 >= cnt) return;
  const int row0 = offs[e] + mt * 128;
  const int mrem = cnt - mt * 128;
  const int n0 = nt * 128;
  const float* __restrict__ W3 = w3 + (size_t)e * D_FF * D_MODEL;

  __shared__ u16 As[128 * BK];
  __shared__ u16 Bs[128 * SK];

  const int tid = threadIdx.x;
  const int lane = tid & 63, wave = tid >> 6;
  const int wm = (wave >> 1) << 6, wn = (wave & 1) << 6;
  const int l16 = lane & 15, quad = lane >> 4;

  const int aoff0 = (tid >> 2) * D_FF + (tid & 3) * 8;
  const int aoff1 = aoff0 + 64 * D_FF;
  u16* const ldsA0 = As + wave * 512;
  u16* const ldsA1 = As + wave * 512 + 2048;
  const u16* gA = H + (size_t)row0 * D_FF;

  const int n2 = (tid & 63) * 2;
  const int kh = (tid >> 6) * 8;
  const float* gB = W3 + (size_t)kh * D_MODEL + n0 + n2;
  u16* const wB = Bs + n2 * SK + kh;

  f32x4 acc[4][4] = {};

  for (int k0 = 0; k0 < D_FF; k0 += BK) {
    gll16(gA + aoff0, ldsA0);
    gll16(gA + aoff1, ldsA1);
    {
      float2 v[8];
      #pragma unroll
      for (int kk = 0; kk < 8; kk++) v[kk] = *(const float2*)(gB + (size_t)kk * D_MODEL);
      bfrag p0, p1;
      #pragma unroll
      for (int kk = 0; kk < 8; kk++) { p0[kk] = (short)f2bf(v[kk].x); p1[kk] = (short)f2bf(v[kk].y); }
      *(bfrag*)wB = p0;
      *(bfrag*)(wB + SK) = p1;
    }
    __syncthreads();
    bfrag b[4];
    #pragma unroll
    for (int j = 0; j < 4; j++)
      b[j] = *(const bfrag*)(Bs + (wn + j * 16 + l16) * SK + quad * 8);
    #pragma unroll
    for (int i = 0; i < 4; i++) {
      bfrag a = *(const bfrag*)(As + (wm + i * 16 + l16) * BK + quad * 8);
      #pragma unroll
      for (int j = 0; j < 4; j++)
        acc[i][j] = __builtin_amdgcn_mfma_f32_16x16x32_bf16(a, b[j], acc[i][j], 0, 0, 0);
    }
    __syncthreads();
    gA += BK;
    gB += (size_t)BK * D_MODEL;
  }

  #pragma unroll
  for (int i = 0; i < 4; i++) {
    #pragma unroll
    for (int p = 0; p < 4; p++) {
      const int mloc = wm + i * 16 + quad * 4 + p;
      if (mloc < mrem) {
        const int r = row0 + mloc;
        const int tok = tokrow[r];
        const float wr = wrow[r];
        float* obase = out + (size_t)tok * D_MODEL + n0 + wn + l16;
        #pragma unroll
        for (int j = 0; j < 4; j++)
          atomicAdd(obase + j * 16, acc[i][j][p] * wr);
      }
    }
  }
}

// ---------------- launcher ----------------
extern "C" void kernel_launch(void* const* d_in, const int* in_sizes, int n_in,
                              void* d_out, int out_size, void* d_ws, size_t ws_size,
                              hipStream_t stream) {
  const float* x  = (const float*)d_in[0];
  const int* eidx = (const int*)d_in[1];
  const float* ew = (const float*)d_in[2];
  const float* w1 = (const float*)d_in[3];
  const float* w2 = (const float*)d_in[4];
  const float* w3 = (const float*)d_in[5];
  float* out = (float*)d_out;

  char* ws = (char*)d_ws;
  int*   rowmap = (int*)(ws);
  int*   tokrow = (int*)(ws + 16384);
  float* wrow   = (float*)(ws + 32768);
  int*   counts = (int*)(ws + 49152);
  int*   offs   = (int*)(ws + 49152 + 64);
  u16*   Xg     = (u16*)(ws + 65536);
  u16*   Hb     = (u16*)(ws + 65536 + (size_t)ROWS * D_MODEL * 2);
  // total ws use: 65536 + 4224*1024*2 + 4224*4096*2 ~= 43.4 MB

  hipMemsetAsync(d_out, 0, (size_t)out_size * sizeof(float), stream);
  k_setup<<<1, 256, 0, stream>>>(eidx, ew, rowmap, tokrow, wrow, counts, offs);
  k_gather<<<ROWS, 256, 0, stream>>>(x, rowmap, Xg);
  k_gemm1<<<dim3(32, D_FF / 128, N_EXPERTS), 256, 0, stream>>>(Xg, w1, w2, counts, offs, Hb);
  k_gemm2<<<dim3(32, D_MODEL / 128, N_EXPERTS), 256, 0, stream>>>(Hb, w3, counts, offs, tokrow, wrow, out);
}

// Round 2
// 620.373 us; speedup vs baseline: 3.1324x; 3.1324x over previous
//
#include <hip/hip_runtime.h>
#include <stdint.h>

#define N_EXPERTS 8
#define D_MODEL 1024
#define D_FF 4096
#define N_TOKENS 2048
#define ASSN 4096          // N_TOKENS * TOP_K
#define ROWS 4224          // ASSN + 128 slack rows for tile overrun
#define BK 32
#define SK 40              // fallback-path padded LDS stride

using bfrag = __attribute__((ext_vector_type(8))) short;   // 8 x bf16
using f32x4 = __attribute__((ext_vector_type(4))) float;
typedef unsigned short u16;

__device__ __forceinline__ u16 f2bf(float f) {
  uint32_t u = __builtin_bit_cast(uint32_t, f);
  u += 0x7fffu + ((u >> 16) & 1u);   // round-to-nearest-even
  return (u16)(u >> 16);
}

__device__ __forceinline__ void gll16(const void* g, void* l) {
  __builtin_amdgcn_global_load_lds(
      (const __attribute__((address_space(1))) void*)g,
      (__attribute__((address_space(3))) void*)l, 16, 0, 0);
}

// ---------------- setup: bucket assignments by expert ----------------
__global__ void k_setup(const int* __restrict__ eidx, const float* __restrict__ ew,
                        int* __restrict__ rowmap, int* __restrict__ arow,
                        int* __restrict__ tokrow, float* __restrict__ wrow,
                        int* __restrict__ counts, int* __restrict__ offs) {
  __shared__ int sc[N_EXPERTS], so[N_EXPERTS];
  int t = threadIdx.x;
  if (t < N_EXPERTS) sc[t] = 0;
  __syncthreads();
  for (int a = t; a < ASSN; a += 256) atomicAdd(&sc[eidx[a]], 1);
  __syncthreads();
  if (t == 0) {
    int run = 0;
    for (int e = 0; e < N_EXPERTS; e++) {
      counts[e] = sc[e]; offs[e] = run; so[e] = run; run += sc[e];
    }
  }
  __syncthreads();
  for (int a = t; a < ASSN; a += 256) {
    int e = eidx[a];
    int p = atomicAdd(&so[e], 1);
    rowmap[p] = a;
    arow[a] = p;
    tokrow[p] = a >> 1;     // TOP_K = 2
    wrow[p] = ew[a];
  }
}

// ---------------- gather x rows -> bf16 packed by expert ----------------
__global__ void k_gather(const float* __restrict__ x, const int* __restrict__ rowmap,
                         u16* __restrict__ Xg) {
  int r = blockIdx.x, t = threadIdx.x;
  uint2 o;
  if (r < ASSN) {
    int tok = rowmap[r] >> 1;
    float4 v = *(const float4*)(x + (size_t)tok * D_MODEL + t * 4);
    o.x = (uint32_t)f2bf(v.x) | ((uint32_t)f2bf(v.y) << 16);
    o.y = (uint32_t)f2bf(v.z) | ((uint32_t)f2bf(v.w) << 16);
  } else {
    o.x = 0u; o.y = 0u;    // zero slack rows
  }
  *(uint2*)(Xg + (size_t)r * D_MODEL + t * 4) = o;
}

// ---------------- transpose+convert: W[e][R][C] fp32 -> Wt[e][C][R] bf16 ----
__global__ void k_trans(const float* __restrict__ W, u16* __restrict__ Wt,
                        int R, int C) {
  __shared__ float tile[64 * 65];
  const int e = blockIdx.z;
  const int c0 = blockIdx.x * 64, r0 = blockIdx.y * 64;
  const float* src = W + ((size_t)e * R + r0) * C + c0;
  u16* dst = Wt + ((size_t)e * C + c0) * R + r0;
  const int t = threadIdx.x;
  const int lr = t >> 4, lc4 = (t & 15) * 4;
  #pragma unroll
  for (int p = 0; p < 4; p++) {
    float4 v = *(const float4*)(src + (size_t)(lr + p * 16) * C + lc4);
    float* d = tile + (lr + p * 16) * 65 + lc4;
    d[0] = v.x; d[1] = v.y; d[2] = v.z; d[3] = v.w;
  }
  __syncthreads();
  const int rr = (t & 7) * 8, cc = t >> 3;   // cc in 0..31
  #pragma unroll
  for (int q = 0; q < 2; q++) {
    const int c = cc + q * 32;
    u16 o[8];
    #pragma unroll
    for (int i = 0; i < 8; i++) o[i] = f2bf(tile[(rr + i) * 65 + c]);
    *(uint4*)(dst + (size_t)c * R + rr) = *(uint4*)o;
  }
}

// ---------------- GEMM1: H = silu(Xg@W1t^T) * (Xg@W2t^T), bf16 out --------
// A: Xg [rows][1024] bf16 ; B: Wt [e][4096 n][1024 k] bf16 (k-contiguous)
__launch_bounds__(256, 2)
__global__ void k_gemm1(const u16* __restrict__ Xg,
                        const u16* __restrict__ Wt1, const u16* __restrict__ Wt2,
                        const int* __restrict__ counts, const int* __restrict__ offs,
                        u16* __restrict__ H) {
  const int e = blockIdx.z, nt = blockIdx.x, mt = blockIdx.y;
  const int cnt = counts[e];
  if (mt * 128 >= cnt) return;
  const int row0 = offs[e] + mt * 128;
  const int mrem = cnt - mt * 128;
  const int n0 = nt * 128;

  __shared__ u16 As[128 * BK];
  __shared__ u16 Bs1[128 * BK];
  __shared__ u16 Bs2[128 * BK];

  const int tid = threadIdx.x;
  const int lane = tid & 63, wave = tid >> 6;
  const int wm = (wave >> 1) << 6, wn = (wave & 1) << 6;
  const int l16 = lane & 15, quad = lane >> 4;

  // staging: row stride 1024 for A and B; offsets cover 128 rows x 32 k
  const int off0 = (tid >> 2) * D_MODEL + (tid & 3) * 8;
  const int off1 = off0 + 64 * D_MODEL;
  u16* const lA0 = As  + wave * 512;  u16* const lA1 = As  + wave * 512 + 2048;
  u16* const lB10 = Bs1 + wave * 512; u16* const lB11 = Bs1 + wave * 512 + 2048;
  u16* const lB20 = Bs2 + wave * 512; u16* const lB21 = Bs2 + wave * 512 + 2048;

  const u16* gA  = Xg  + (size_t)row0 * D_MODEL;
  const u16* gB1 = Wt1 + ((size_t)e * D_FF + n0) * D_MODEL;
  const u16* gB2 = Wt2 + ((size_t)e * D_FF + n0) * D_MODEL;

  f32x4 acc1[4][4] = {};
  f32x4 acc2[4][4] = {};

  for (int k0 = 0; k0 < D_MODEL; k0 += BK) {
    gll16(gA  + off0, lA0);  gll16(gA  + off1, lA1);
    gll16(gB1 + off0, lB10); gll16(gB1 + off1, lB11);
    gll16(gB2 + off0, lB20); gll16(gB2 + off1, lB21);
    __syncthreads();
    bfrag b1[4], b2[4];
    #pragma unroll
    for (int j = 0; j < 4; j++) {
      b1[j] = *(const bfrag*)(Bs1 + (wn + j * 16 + l16) * BK + quad * 8);
      b2[j] = *(const bfrag*)(Bs2 + (wn + j * 16 + l16) * BK + quad * 8);
    }
    #pragma unroll
    for (int i = 0; i < 4; i++) {
      bfrag a = *(const bfrag*)(As + (wm + i * 16 + l16) * BK + quad * 8);
      #pragma unroll
      for (int j = 0; j < 4; j++) {
        acc1[i][j] = __builtin_amdgcn_mfma_f32_16x16x32_bf16(a, b1[j], acc1[i][j], 0, 0, 0);
        acc2[i][j] = __builtin_amdgcn_mfma_f32_16x16x32_bf16(a, b2[j], acc2[i][j], 0, 0, 0);
      }
    }
    __syncthreads();
    gA += BK; gB1 += BK; gB2 += BK;
  }

  #pragma unroll
  for (int i = 0; i < 4; i++) {
    #pragma unroll
    for (int p = 0; p < 4; p++) {
      const int mloc = wm + i * 16 + quad * 4 + p;
      if (mloc < mrem) {
        u16* dst = H + (size_t)(row0 + mloc) * D_FF + n0 + wn + l16;
        #pragma unroll
        for (int j = 0; j < 4; j++) {
          float g = acc1[i][j][p];
          float vv = acc2[i][j][p];
          float h = g / (1.0f + __expf(-g)) * vv;
          dst[j * 16] = f2bf(h);
        }
      }
    }
  }
}

// ---------------- GEMM2: Y[kh] = H(khalf) @ W3t^T, fp32 out, split-K x2 ----
// A: H [rows][4096] bf16 ; B: Wt3 [e][1024 n][4096 k] bf16
__launch_bounds__(256, 2)
__global__ void k_gemm2(const u16* __restrict__ H, const u16* __restrict__ Wt3,
                        const int* __restrict__ counts, const int* __restrict__ offs,
                        float* __restrict__ Y0, float* __restrict__ Y1) {
  const int e = blockIdx.z >> 1, kh = blockIdx.z & 1;
  const int nt = blockIdx.x, mt = blockIdx.y;
  const int cnt = counts[e];
  if (mt * 128 >= cnt) return;
  const int row0 = offs[e] + mt * 128;
  const int mrem = cnt - mt * 128;
  const int n0 = nt * 128;
  float* __restrict__ Y = kh ? Y1 : Y0;

  __shared__ u16 As[128 * BK];
  __shared__ u16 Bs[128 * BK];

  const int tid = threadIdx.x;
  const int lane = tid & 63, wave = tid >> 6;
  const int wm = (wave >> 1) << 6, wn = (wave & 1) << 6;
  const int l16 = lane & 15, quad = lane >> 4;

  const int off0 = (tid >> 2) * D_FF + (tid & 3) * 8;
  const int off1 = off0 + 64 * D_FF;
  u16* const lA0 = As + wave * 512; u16* const lA1 = As + wave * 512 + 2048;
  u16* const lB0 = Bs + wave * 512; u16* const lB1 = Bs + wave * 512 + 2048;

  const u16* gA = H + (size_t)row0 * D_FF + kh * 2048;
  const u16* gB = Wt3 + ((size_t)e * D_MODEL + n0) * D_FF + kh * 2048;

  f32x4 acc[4][4] = {};

  for (int k0 = 0; k0 < 2048; k0 += BK) {
    gll16(gA + off0, lA0); gll16(gA + off1, lA1);
    gll16(gB + off0, lB0); gll16(gB + off1, lB1);
    __syncthreads();
    bfrag b[4];
    #pragma unroll
    for (int j = 0; j < 4; j++)
      b[j] = *(const bfrag*)(Bs + (wn + j * 16 + l16) * BK + quad * 8);
    #pragma unroll
    for (int i = 0; i < 4; i++) {
      bfrag a = *(const bfrag*)(As + (wm + i * 16 + l16) * BK + quad * 8);
      #pragma unroll
      for (int j = 0; j < 4; j++)
        acc[i][j] = __builtin_amdgcn_mfma_f32_16x16x32_bf16(a, b[j], acc[i][j], 0, 0, 0);
    }
    __syncthreads();
    gA += BK; gB += BK;
  }

  #pragma unroll
  for (int i = 0; i < 4; i++) {
    #pragma unroll
    for (int p = 0; p < 4; p++) {
      const int mloc = wm + i * 16 + quad * 4 + p;
      if (mloc < mrem) {
        float* dst = Y + (size_t)(row0 + mloc) * D_MODEL + n0 + wn + l16;
        #pragma unroll
        for (int j = 0; j < 4; j++) dst[j * 16] = acc[i][j][p];
      }
    }
  }
}

// ---------------- combine: out[tok] = sum_j w_j * (Y0+Y1)[arow] ----------
__global__ void k_combine(const float* __restrict__ Y0, const float* __restrict__ Y1,
                          const int* __restrict__ arow, const float* __restrict__ ew,
                          float* __restrict__ out) {
  const int tk = blockIdx.x;
  const int d = threadIdx.x * 4;
  const int a0 = tk * 2, a1 = tk * 2 + 1;
  const int r0 = arow[a0], r1 = arow[a1];
  const float w0 = ew[a0], w1 = ew[a1];
  const float4 p0 = *(const float4*)(Y0 + (size_t)r0 * D_MODEL + d);
  const float4 q0 = *(const float4*)(Y1 + (size_t)r0 * D_MODEL + d);
  const float4 p1 = *(const float4*)(Y0 + (size_t)r1 * D_MODEL + d);
  const float4 q1 = *(const float4*)(Y1 + (size_t)r1 * D_MODEL + d);
  float4 r;
  r.x = w0 * (p0.x + q0.x) + w1 * (p1.x + q1.x);
  r.y = w0 * (p0.y + q0.y) + w1 * (p1.y + q1.y);
  r.z = w0 * (p0.z + q0.z) + w1 * (p1.z + q1.z);
  r.w = w0 * (p0.w + q0.w) + w1 * (p1.w + q1.w);
  *(float4*)(out + (size_t)tk * D_MODEL + d) = r;
}

// ======== fallback kernels (round-1, on-the-fly fp32->bf16 convert) ========
__launch_bounds__(256, 2)
__global__ void k_gemm1_fb(const u16* __restrict__ Xg,
                           const float* __restrict__ w1, const float* __restrict__ w2,
                           const int* __restrict__ counts, const int* __restrict__ offs,
                           u16* __restrict__ H) {
  const int e = blockIdx.z, mt = blockIdx.x, nt = blockIdx.y;
  const int cnt = counts[e];
  if (mt * 128 >= cnt) return;
  const int row0 = offs[e] + mt * 128;
  const int mrem = cnt - mt * 128;
  const int n0 = nt * 128;
  const float* __restrict__ W1 = w1 + (size_t)e * D_MODEL * D_FF;
  const float* __restrict__ W2 = w2 + (size_t)e * D_MODEL * D_FF;
  __shared__ u16 As[128 * BK];
  __shared__ u16 Bs1[128 * SK];
  __shared__ u16 Bs2[128 * SK];
  const int tid = threadIdx.x;
  const int lane = tid & 63, wave = tid >> 6;
  const int wm = (wave >> 1) << 6, wn = (wave & 1) << 6;
  const int l16 = lane & 15, quad = lane >> 4;
  const int aoff0 = (tid >> 2) * D_MODEL + (tid & 3) * 8;
  const int aoff1 = aoff0 + 64 * D_MODEL;
  u16* const ldsA0 = As + wave * 512;
  u16* const ldsA1 = As + wave * 512 + 2048;
  const u16* gA = Xg + (size_t)row0 * D_MODEL;
  const int n2 = (tid & 63) * 2;
  const int kh = (tid >> 6) * 8;
  const float* gB1 = W1 + (size_t)kh * D_FF + n0 + n2;
  const float* gB2 = W2 + (size_t)kh * D_FF + n0 + n2;
  u16* const wB1 = Bs1 + n2 * SK + kh;
  u16* const wB2 = Bs2 + n2 * SK + kh;
  f32x4 acc1[4][4] = {};
  f32x4 acc2[4][4] = {};
  for (int k0 = 0; k0 < D_MODEL; k0 += BK) {
    gll16(gA + aoff0, ldsA0);
    gll16(gA + aoff1, ldsA1);
    {
      float2 v[8];
      #pragma unroll
      for (int kk = 0; kk < 8; kk++) v[kk] = *(const float2*)(gB1 + (size_t)kk * D_FF);
      bfrag p0, p1;
      #pragma unroll
      for (int kk = 0; kk < 8; kk++) { p0[kk] = (short)f2bf(v[kk].x); p1[kk] = (short)f2bf(v[kk].y); }
      *(bfrag*)wB1 = p0; *(bfrag*)(wB1 + SK) = p1;
    }
    {
      float2 v[8];
      #pragma unroll
      for (int kk = 0; kk < 8; kk++) v[kk] = *(const float2*)(gB2 + (size_t)kk * D_FF);
      bfrag p0, p1;
      #pragma unroll
      for (int kk = 0; kk < 8; kk++) { p0[kk] = (short)f2bf(v[kk].x); p1[kk] = (short)f2bf(v[kk].y); }
      *(bfrag*)wB2 = p0; *(bfrag*)(wB2 + SK) = p1;
    }
    __syncthreads();
    bfrag b1[4], b2[4];
    #pragma unroll
    for (int j = 0; j < 4; j++) {
      b1[j] = *(const bfrag*)(Bs1 + (wn + j * 16 + l16) * SK + quad * 8);
      b2[j] = *(const bfrag*)(Bs2 + (wn + j * 16 + l16) * SK + quad * 8);
    }
    #pragma unroll
    for (int i = 0; i < 4; i++) {
      bfrag a = *(const bfrag*)(As + (wm + i * 16 + l16) * BK + quad * 8);
      #pragma unroll
      for (int j = 0; j < 4; j++) {
        acc1[i][j] = __builtin_amdgcn_mfma_f32_16x16x32_bf16(a, b1[j], acc1[i][j], 0, 0, 0);
        acc2[i][j] = __builtin_amdgcn_mfma_f32_16x16x32_bf16(a, b2[j], acc2[i][j], 0, 0, 0);
      }
    }
    __syncthreads();
    gA += BK; gB1 += (size_t)BK * D_FF; gB2 += (size_t)BK * D_FF;
  }
  #pragma unroll
  for (int i = 0; i < 4; i++) {
    #pragma unroll
    for (int p = 0; p < 4; p++) {
      const int mloc = wm + i * 16 + quad * 4 + p;
      if (mloc < mrem) {
        u16* dst = H + (size_t)(row0 + mloc) * D_FF + n0 + wn + l16;
        #pragma unroll
        for (int j = 0; j < 4; j++) {
          float g = acc1[i][j][p];
          float vv = acc2[i][j][p];
          float h = g / (1.0f + __expf(-g)) * vv;
          dst[j * 16] = f2bf(h);
        }
      }
    }
  }
}

__launch_bounds__(256, 2)
__global__ void k_gemm2_fb(const u16* __restrict__ H,
                           const float* __restrict__ w3,
                           const int* __restrict__ counts, const int* __restrict__ offs,
                           const int* __restrict__ tokrow, const float* __restrict__ wrow,
                           float* __restrict__ out) {
  const int e = blockIdx.z, mt = blockIdx.x, nt = blockIdx.y;
  const int cnt = counts[e];
  if (mt * 128 >= cnt) return;
  const int row0 = offs[e] + mt * 128;
  const int mrem = cnt - mt * 128;
  const int n0 = nt * 128;
  const float* __restrict__ W3 = w3 + (size_t)e * D_FF * D_MODEL;
  __shared__ u16 As[128 * BK];
  __shared__ u16 Bs[128 * SK];
  const int tid = threadIdx.x;
  const int lane = tid & 63, wave = tid >> 6;
  const int wm = (wave >> 1) << 6, wn = (wave & 1) << 6;
  const int l16 = lane & 15, quad = lane >> 4;
  const int aoff0 = (tid >> 2) * D_FF + (tid & 3) * 8;
  const int aoff1 = aoff0 + 64 * D_FF;
  u16* const ldsA0 = As + wave * 512;
  u16* const ldsA1 = As + wave * 512 + 2048;
  const u16* gA = H + (size_t)row0 * D_FF;
  const int n2 = (tid & 63) * 2;
  const int kh = (tid >> 6) * 8;
  const float* gB = W3 + (size_t)kh * D_MODEL + n0 + n2;
  u16* const wB = Bs + n2 * SK + kh;
  f32x4 acc[4][4] = {};
  for (int k0 = 0; k0 < D_FF; k0 += BK) {
    gll16(gA + aoff0, ldsA0);
    gll16(gA + aoff1, ldsA1);
    {
      float2 v[8];
      #pragma unroll
      for (int kk = 0; kk < 8; kk++) v[kk] = *(const float2*)(gB + (size_t)kk * D_MODEL);
      bfrag p0, p1;
      #pragma unroll
      for (int kk = 0; kk < 8; kk++) { p0[kk] = (short)f2bf(v[kk].x); p1[kk] = (short)f2bf(v[kk].y); }
      *(bfrag*)wB = p0; *(bfrag*)(wB + SK) = p1;
    }
    __syncthreads();
    bfrag b[4];
    #pragma unroll
    for (int j = 0; j < 4; j++)
      b[j] = *(const bfrag*)(Bs + (wn + j * 16 + l16) * SK + quad * 8);
    #pragma unroll
    for (int i = 0; i < 4; i++) {
      bfrag a = *(const bfrag*)(As + (wm + i * 16 + l16) * BK + quad * 8);
      #pragma unroll
      for (int j = 0; j < 4; j++)
        acc[i][j] = __builtin_amdgcn_mfma_f32_16x16x32_bf16(a, b[j], acc[i][j], 0, 0, 0);
    }
    __syncthreads();
    gA += BK; gB += (size_t)BK * D_MODEL;
  }
  #pragma unroll
  for (int i = 0; i < 4; i++) {
    #pragma unroll
    for (int p = 0; p < 4; p++) {
      const int mloc = wm + i * 16 + quad * 4 + p;
      if (mloc < mrem) {
        const int r = row0 + mloc;
        const int tok = tokrow[r];
        const float wr = wrow[r];
        float* obase = out + (size_t)tok * D_MODEL + n0 + wn + l16;
        #pragma unroll
        for (int j = 0; j < 4; j++)
          atomicAdd(obase + j * 16, acc[i][j][p] * wr);
      }
    }
  }
}

// ---------------- launcher ----------------
extern "C" void kernel_launch(void* const* d_in, const int* in_sizes, int n_in,
                              void* d_out, int out_size, void* d_ws, size_t ws_size,
                              hipStream_t stream) {
  const float* x  = (const float*)d_in[0];
  const int* eidx = (const int*)d_in[1];
  const float* ew = (const float*)d_in[2];
  const float* w1 = (const float*)d_in[3];
  const float* w2 = (const float*)d_in[4];
  const float* w3 = (const float*)d_in[5];
  float* out = (float*)d_out;

  char* ws = (char*)d_ws;
  int*   rowmap = (int*)(ws);
  int*   arow   = (int*)(ws + 16384);
  int*   tokrow = (int*)(ws + 32768);
  float* wrow   = (float*)(ws + 49152);
  int*   counts = (int*)(ws + 65536);
  int*   offs   = (int*)(ws + 65536 + 64);
  const size_t D0 = 131072;
  const size_t SZ_XG = (size_t)ROWS * D_MODEL * 2;   //  8,650,752
  const size_t SZ_HB = (size_t)ROWS * D_FF * 2;      // 34,603,008
  const size_t SZ_Y  = (size_t)ROWS * D_MODEL * 4;   // 17,301,504
  const size_t SZ_WT = (size_t)N_EXPERTS * D_MODEL * D_FF * 2;  // 67,108,864
  u16*   Xg  = (u16*)(ws + D0);
  u16*   Hb  = (u16*)(ws + D0 + SZ_XG);
  float* Y0  = (float*)(ws + D0 + SZ_XG + SZ_HB);
  float* Y1  = (float*)(ws + D0 + SZ_XG + SZ_HB + SZ_Y);
  u16*   WtA = (u16*)(ws + D0 + SZ_XG + SZ_HB + 2 * SZ_Y);           // Wt1, later Wt3
  u16*   WtB = (u16*)(ws + D0 + SZ_XG + SZ_HB + 2 * SZ_Y + SZ_WT);   // Wt2
  const size_t NEED = D0 + SZ_XG + SZ_HB + 2 * SZ_Y + 2 * SZ_WT;     // ~212.2 MB

  k_setup<<<1, 256, 0, stream>>>(eidx, ew, rowmap, arow, tokrow, wrow, counts, offs);
  k_gather<<<ROWS, 256, 0, stream>>>(x, rowmap, Xg);

  if (ws_size >= NEED) {
    // fast path: pre-transposed bf16 weights, pure global_load_lds GEMMs
    k_trans<<<dim3(D_FF / 64, D_MODEL / 64, N_EXPERTS), 256, 0, stream>>>(w1, WtA, D_MODEL, D_FF);
    k_trans<<<dim3(D_FF / 64, D_MODEL / 64, N_EXPERTS), 256, 0, stream>>>(w2, WtB, D_MODEL, D_FF);
    k_gemm1<<<dim3(D_FF / 128, 32, N_EXPERTS), 256, 0, stream>>>(Xg, WtA, WtB, counts, offs, Hb);
    k_trans<<<dim3(D_MODEL / 64, D_FF / 64, N_EXPERTS), 256, 0, stream>>>(w3, WtA, D_FF, D_MODEL);
    k_gemm2<<<dim3(D_MODEL / 128, 32, N_EXPERTS * 2), 256, 0, stream>>>(Hb, WtA, counts, offs, Y0, Y1);
    k_combine<<<N_TOKENS, 256, 0, stream>>>(Y0, Y1, arow, ew, out);
  } else {
    // fallback: round-1 kernels (on-the-fly convert, atomic combine)
    hipMemsetAsync(d_out, 0, (size_t)out_size * sizeof(float), stream);
    k_gemm1_fb<<<dim3(32, D_FF / 128, N_EXPERTS), 256, 0, stream>>>(Xg, w1, w2, counts, offs, Hb);
    k_gemm2_fb<<<dim3(32, D_MODEL / 128, N_EXPERTS), 256, 0, stream>>>(Hb, w3, counts, offs, tokrow, wrow, out);
  }
}

// Round 3
// 618.624 us; speedup vs baseline: 3.1413x; 1.0028x over previous
//
#include <hip/hip_runtime.h>
#include <stdint.h>

#define N_EXPERTS 8
#define D_MODEL 1024
#define D_FF 4096
#define N_TOKENS 2048
#define ASSN 4096          // N_TOKENS * TOP_K
#define ROWS 4224          // ASSN + 128 slack rows for tile overrun
#define BK 32
#define SKB 36             // padded B-tile row stride (elems): conflict-free ds_write

using bfrag = __attribute__((ext_vector_type(8))) short;   // 8 x bf16
using f32x4 = __attribute__((ext_vector_type(4))) float;
typedef unsigned short u16;

__device__ __forceinline__ u16 f2bf(float f) {
  uint32_t u = __builtin_bit_cast(uint32_t, f);
  u += 0x7fffu + ((u >> 16) & 1u);   // round-to-nearest-even
  return (u16)(u >> 16);
}

__device__ __forceinline__ void gll16(const void* g, void* l) {
  __builtin_amdgcn_global_load_lds(
      (const __attribute__((address_space(1))) void*)g,
      (__attribute__((address_space(3))) void*)l, 16, 0, 0);
}

__device__ __forceinline__ bfrag ldb64x2(const u16* p) {
  union { bfrag f; uint2 u[2]; } t;
  t.u[0] = *(const uint2*)p;
  t.u[1] = *(const uint2*)(p + 4);
  return t.f;
}
__device__ __forceinline__ void stb64x2(u16* p, bfrag f) {
  union { bfrag f; uint2 u[2]; } t; t.f = f;
  *(uint2*)p = t.u[0];
  *(uint2*)(p + 4) = t.u[1];
}

// ---------------- setup: bucket assignments by expert ----------------
__global__ void k_setup(const int* __restrict__ eidx, const float* __restrict__ ew,
                        int* __restrict__ rowmap, int* __restrict__ arow,
                        int* __restrict__ counts, int* __restrict__ offs) {
  __shared__ int sc[N_EXPERTS], so[N_EXPERTS];
  int t = threadIdx.x;
  if (t < N_EXPERTS) sc[t] = 0;
  __syncthreads();
  for (int a = t; a < ASSN; a += 256) atomicAdd(&sc[eidx[a]], 1);
  __syncthreads();
  if (t == 0) {
    int run = 0;
    for (int e = 0; e < N_EXPERTS; e++) {
      counts[e] = sc[e]; offs[e] = run; so[e] = run; run += sc[e];
    }
  }
  __syncthreads();
  for (int a = t; a < ASSN; a += 256) {
    int e = eidx[a];
    int p = atomicAdd(&so[e], 1);
    rowmap[p] = a;
    arow[a] = p;
  }
}

// ---------------- gather x rows -> bf16 packed by expert ----------------
__global__ void k_gather(const float* __restrict__ x, const int* __restrict__ rowmap,
                         u16* __restrict__ Xg) {
  int r = blockIdx.x, t = threadIdx.x;
  uint2 o;
  if (r < ASSN) {
    int tok = rowmap[r] >> 1;   // TOP_K = 2
    float4 v = *(const float4*)(x + (size_t)tok * D_MODEL + t * 4);
    o.x = (uint32_t)f2bf(v.x) | ((uint32_t)f2bf(v.y) << 16);
    o.y = (uint32_t)f2bf(v.z) | ((uint32_t)f2bf(v.w) << 16);
  } else {
    o.x = 0u; o.y = 0u;        // zero slack rows
  }
  *(uint2*)(Xg + (size_t)r * D_MODEL + t * 4) = o;
}

// ---- GEMM1: H = silu(Xg@W1) * (Xg@W2), fused fp32->bf16, dbuf pipeline ----
__launch_bounds__(256, 2)
__global__ void k_gemm1(const u16* __restrict__ Xg,
                        const float* __restrict__ w1, const float* __restrict__ w2,
                        const int* __restrict__ counts, const int* __restrict__ offs,
                        u16* __restrict__ H) {
  const int e = blockIdx.z, nt = blockIdx.x, mt = blockIdx.y;
  const int cnt = counts[e];
  if (mt * 128 >= cnt) return;
  const int row0 = offs[e] + mt * 128;
  const int mrem = cnt - mt * 128;
  const int n0 = nt * 128;

  __shared__ u16 As[2][128 * BK];     // 16 KB
  __shared__ u16 Bs1[2][128 * SKB];   // 18 KB
  __shared__ u16 Bs2[2][128 * SKB];   // 18 KB

  const int tid = threadIdx.x;
  const int lane = tid & 63, wave = tid >> 6;
  const int wm = (wave >> 1) << 6, wn = (wave & 1) << 6;
  const int l16 = lane & 15, quad = lane >> 4;

  const int off0 = (tid >> 2) * D_MODEL + (tid & 3) * 8;
  const int off1 = off0 + 64 * D_MODEL;
  const int ldso = wave * 512;

  const u16* gA = Xg + (size_t)row0 * D_MODEL;

  const int n2 = lane * 2;           // even B-row this thread owns
  const int kh = wave * 8;           // k-rows [kh, kh+8)
  const float* pB1 = w1 + (size_t)e * D_MODEL * D_FF + (size_t)kh * D_FF + n0 + n2;
  const float* pB2 = w2 + (size_t)e * D_MODEL * D_FF + (size_t)kh * D_FF + n0 + n2;
  const size_t bstep = (size_t)BK * D_FF;

  f32x4 acc1[4][4] = {};
  f32x4 acc2[4][4] = {};

  float2 v1[8], v2[8];
  // prologue: load B(0) regs
  #pragma unroll
  for (int kk = 0; kk < 8; kk++) {
    v1[kk] = *(const float2*)(pB1 + (size_t)kk * D_FF);
    v2[kk] = *(const float2*)(pB2 + (size_t)kk * D_FF);
  }
  pB1 += bstep; pB2 += bstep;
  // stage A(0), B(0) into buf0
  gll16(gA + off0, &As[0][ldso]);
  gll16(gA + off1, &As[0][ldso + 2048]);
  {
    bfrag p0, p1;
    #pragma unroll
    for (int kk = 0; kk < 8; kk++) { p0[kk] = (short)f2bf(v1[kk].x); p1[kk] = (short)f2bf(v1[kk].y); }
    *(bfrag*)&Bs1[0][n2 * SKB + kh] = p0;
    stb64x2(&Bs1[0][(n2 + 1) * SKB + kh], p1);
    #pragma unroll
    for (int kk = 0; kk < 8; kk++) { p0[kk] = (short)f2bf(v2[kk].x); p1[kk] = (short)f2bf(v2[kk].y); }
    *(bfrag*)&Bs2[0][n2 * SKB + kh] = p0;
    stb64x2(&Bs2[0][(n2 + 1) * SKB + kh], p1);
  }
  // prefetch B(1) regs
  #pragma unroll
  for (int kk = 0; kk < 8; kk++) {
    v1[kk] = *(const float2*)(pB1 + (size_t)kk * D_FF);
    v2[kk] = *(const float2*)(pB2 + (size_t)kk * D_FF);
  }
  pB1 += bstep; pB2 += bstep;
  __syncthreads();

  const u16* gAn = gA + BK;
  #pragma unroll 2
  for (int ks = 0; ks < 32; ks++) {
    const int c = ks & 1;
    if (ks < 31) {
      // stage step ks+1 into buf[1-c]
      gll16(gAn + off0, &As[1 - c][ldso]);
      gll16(gAn + off1, &As[1 - c][ldso + 2048]);
      gAn += BK;
      bfrag p0, p1;
      #pragma unroll
      for (int kk = 0; kk < 8; kk++) { p0[kk] = (short)f2bf(v1[kk].x); p1[kk] = (short)f2bf(v1[kk].y); }
      *(bfrag*)&Bs1[1 - c][n2 * SKB + kh] = p0;
      stb64x2(&Bs1[1 - c][(n2 + 1) * SKB + kh], p1);
      #pragma unroll
      for (int kk = 0; kk < 8; kk++) { p0[kk] = (short)f2bf(v2[kk].x); p1[kk] = (short)f2bf(v2[kk].y); }
      *(bfrag*)&Bs2[1 - c][n2 * SKB + kh] = p0;
      stb64x2(&Bs2[1 - c][(n2 + 1) * SKB + kh], p1);
      if (ks < 30) {
        // prefetch B regs for step ks+2 (overlaps MFMA below)
        #pragma unroll
        for (int kk = 0; kk < 8; kk++) {
          v1[kk] = *(const float2*)(pB1 + (size_t)kk * D_FF);
          v2[kk] = *(const float2*)(pB2 + (size_t)kk * D_FF);
        }
        pB1 += bstep; pB2 += bstep;
      }
    }
    // consume buf[c]
    bfrag b1[4], b2[4];
    #pragma unroll
    for (int j = 0; j < 4; j++) {
      b1[j] = ldb64x2(&Bs1[c][(wn + j * 16 + l16) * SKB + quad * 8]);
      b2[j] = ldb64x2(&Bs2[c][(wn + j * 16 + l16) * SKB + quad * 8]);
    }
    #pragma unroll
    for (int i = 0; i < 4; i++) {
      bfrag a = *(const bfrag*)&As[c][(wm + i * 16 + l16) * BK + quad * 8];
      #pragma unroll
      for (int j = 0; j < 4; j++) {
        acc1[i][j] = __builtin_amdgcn_mfma_f32_16x16x32_bf16(a, b1[j], acc1[i][j], 0, 0, 0);
        acc2[i][j] = __builtin_amdgcn_mfma_f32_16x16x32_bf16(a, b2[j], acc2[i][j], 0, 0, 0);
      }
    }
    __syncthreads();
  }

  // epilogue: h = silu(g)*v, store bf16. C/D layout: col=lane&15, row=quad*4+reg
  #pragma unroll
  for (int i = 0; i < 4; i++) {
    #pragma unroll
    for (int p = 0; p < 4; p++) {
      const int mloc = wm + i * 16 + quad * 4 + p;
      if (mloc < mrem) {
        u16* dst = H + (size_t)(row0 + mloc) * D_FF + n0 + wn + l16;
        #pragma unroll
        for (int j = 0; j < 4; j++) {
          float g = acc1[i][j][p];
          float vv = acc2[i][j][p];
          float h = g / (1.0f + __expf(-g)) * vv;
          dst[j * 16] = f2bf(h);
        }
      }
    }
  }
}

// ---- GEMM2: Y[kh] = H(k-half) @ W3, fused fp32->bf16, split-K x2 ----
__launch_bounds__(256, 2)
__global__ void k_gemm2(const u16* __restrict__ H, const float* __restrict__ w3,
                        const int* __restrict__ counts, const int* __restrict__ offs,
                        float* __restrict__ Y0, float* __restrict__ Y1) {
  const int e = blockIdx.z >> 1, khalf = blockIdx.z & 1;
  const int nt = blockIdx.x, mt = blockIdx.y;
  const int cnt = counts[e];
  if (mt * 128 >= cnt) return;
  const int row0 = offs[e] + mt * 128;
  const int mrem = cnt - mt * 128;
  const int n0 = nt * 128;
  float* __restrict__ Y = khalf ? Y1 : Y0;

  __shared__ u16 As[2][128 * BK];
  __shared__ u16 Bs[2][128 * SKB];

  const int tid = threadIdx.x;
  const int lane = tid & 63, wave = tid >> 6;
  const int wm = (wave >> 1) << 6, wn = (wave & 1) << 6;
  const int l16 = lane & 15, quad = lane >> 4;

  const int off0 = (tid >> 2) * D_FF + (tid & 3) * 8;
  const int off1 = off0 + 64 * D_FF;
  const int ldso = wave * 512;

  const u16* gA = H + (size_t)row0 * D_FF + khalf * 2048;

  const int n2 = lane * 2;
  const int kh = wave * 8;
  const float* pB = w3 + (size_t)e * D_FF * D_MODEL
                  + (size_t)(khalf * 2048 + kh) * D_MODEL + n0 + n2;
  const size_t bstep = (size_t)BK * D_MODEL;

  f32x4 acc[4][4] = {};

  float2 v[8];
  #pragma unroll
  for (int kk = 0; kk < 8; kk++) v[kk] = *(const float2*)(pB + (size_t)kk * D_MODEL);
  pB += bstep;
  gll16(gA + off0, &As[0][ldso]);
  gll16(gA + off1, &As[0][ldso + 2048]);
  {
    bfrag p0, p1;
    #pragma unroll
    for (int kk = 0; kk < 8; kk++) { p0[kk] = (short)f2bf(v[kk].x); p1[kk] = (short)f2bf(v[kk].y); }
    *(bfrag*)&Bs[0][n2 * SKB + kh] = p0;
    stb64x2(&Bs[0][(n2 + 1) * SKB + kh], p1);
  }
  #pragma unroll
  for (int kk = 0; kk < 8; kk++) v[kk] = *(const float2*)(pB + (size_t)kk * D_MODEL);
  pB += bstep;
  __syncthreads();

  const u16* gAn = gA + BK;
  #pragma unroll 2
  for (int ks = 0; ks < 64; ks++) {
    const int c = ks & 1;
    if (ks < 63) {
      gll16(gAn + off0, &As[1 - c][ldso]);
      gll16(gAn + off1, &As[1 - c][ldso + 2048]);
      gAn += BK;
      bfrag p0, p1;
      #pragma unroll
      for (int kk = 0; kk < 8; kk++) { p0[kk] = (short)f2bf(v[kk].x); p1[kk] = (short)f2bf(v[kk].y); }
      *(bfrag*)&Bs[1 - c][n2 * SKB + kh] = p0;
      stb64x2(&Bs[1 - c][(n2 + 1) * SKB + kh], p1);
      if (ks < 62) {
        #pragma unroll
        for (int kk = 0; kk < 8; kk++) v[kk] = *(const float2*)(pB + (size_t)kk * D_MODEL);
        pB += bstep;
      }
    }
    bfrag b[4];
    #pragma unroll
    for (int j = 0; j < 4; j++)
      b[j] = ldb64x2(&Bs[c][(wn + j * 16 + l16) * SKB + quad * 8]);
    #pragma unroll
    for (int i = 0; i < 4; i++) {
      bfrag a = *(const bfrag*)&As[c][(wm + i * 16 + l16) * BK + quad * 8];
      #pragma unroll
      for (int j = 0; j < 4; j++)
        acc[i][j] = __builtin_amdgcn_mfma_f32_16x16x32_bf16(a, b[j], acc[i][j], 0, 0, 0);
    }
    __syncthreads();
  }

  #pragma unroll
  for (int i = 0; i < 4; i++) {
    #pragma unroll
    for (int p = 0; p < 4; p++) {
      const int mloc = wm + i * 16 + quad * 4 + p;
      if (mloc < mrem) {
        float* dst = Y + (size_t)(row0 + mloc) * D_MODEL + n0 + wn + l16;
        #pragma unroll
        for (int j = 0; j < 4; j++) dst[j * 16] = acc[i][j][p];
      }
    }
  }
}

// ---------------- combine: out[tok] = sum_j w_j * (Y0+Y1)[arow] ----------
__global__ void k_combine(const float* __restrict__ Y0, const float* __restrict__ Y1,
                          const int* __restrict__ arow, const float* __restrict__ ew,
                          float* __restrict__ out) {
  const int tk = blockIdx.x;
  const int d = threadIdx.x * 4;
  const int a0 = tk * 2, a1 = tk * 2 + 1;
  const int r0 = arow[a0], r1 = arow[a1];
  const float w0 = ew[a0], w1 = ew[a1];
  const float4 p0 = *(const float4*)(Y0 + (size_t)r0 * D_MODEL + d);
  const float4 q0 = *(const float4*)(Y1 + (size_t)r0 * D_MODEL + d);
  const float4 p1 = *(const float4*)(Y0 + (size_t)r1 * D_MODEL + d);
  const float4 q1 = *(const float4*)(Y1 + (size_t)r1 * D_MODEL + d);
  float4 r;
  r.x = w0 * (p0.x + q0.x) + w1 * (p1.x + q1.x);
  r.y = w0 * (p0.y + q0.y) + w1 * (p1.y + q1.y);
  r.z = w0 * (p0.z + q0.z) + w1 * (p1.z + q1.z);
  r.w = w0 * (p0.w + q0.w) + w1 * (p1.w + q1.w);
  *(float4*)(out + (size_t)tk * D_MODEL + d) = r;
}

// ---------------- launcher ----------------
extern "C" void kernel_launch(void* const* d_in, const int* in_sizes, int n_in,
                              void* d_out, int out_size, void* d_ws, size_t ws_size,
                              hipStream_t stream) {
  const float* x  = (const float*)d_in[0];
  const int* eidx = (const int*)d_in[1];
  const float* ew = (const float*)d_in[2];
  const float* w1 = (const float*)d_in[3];
  const float* w2 = (const float*)d_in[4];
  const float* w3 = (const float*)d_in[5];
  float* out = (float*)d_out;

  char* ws = (char*)d_ws;
  int*   rowmap = (int*)(ws);
  int*   arow   = (int*)(ws + 16384);
  int*   counts = (int*)(ws + 32768);
  int*   offs   = (int*)(ws + 32768 + 64);
  const size_t D0 = 65536;
  const size_t SZ_XG = (size_t)ROWS * D_MODEL * 2;   //  8,650,752
  const size_t SZ_HB = (size_t)ROWS * D_FF * 2;      // 34,603,008
  const size_t SZ_Y  = (size_t)ROWS * D_MODEL * 4;   // 17,301,504
  u16*   Xg = (u16*)(ws + D0);
  u16*   Hb = (u16*)(ws + D0 + SZ_XG);
  float* Y0 = (float*)(ws + D0 + SZ_XG + SZ_HB);
  float* Y1 = (float*)(ws + D0 + SZ_XG + SZ_HB + SZ_Y);
  // total ws use ~78 MB

  k_setup<<<1, 256, 0, stream>>>(eidx, ew, rowmap, arow, counts, offs);
  k_gather<<<ROWS, 256, 0, stream>>>(x, rowmap, Xg);
  // nt-major grids: blocks sharing a weight slice differ by a multiple of 8
  // in linear index -> same XCD -> weight re-reads are L2 hits.
  k_gemm1<<<dim3(D_FF / 128, 32, N_EXPERTS), 256, 0, stream>>>(Xg, w1, w2, counts, offs, Hb);
  k_gemm2<<<dim3(D_MODEL / 128, 32, N_EXPERTS * 2), 256, 0, stream>>>(Hb, w3, counts, offs, Y0, Y1);
  k_combine<<<N_TOKENS, 256, 0, stream>>>(Y0, Y1, arow, ew, out);
}